// Round 3
// baseline (288.605 us; speedup 1.0000x reference)
//
#include <hip/hip_runtime.h>
#include <hip/hip_bf16.h>

// out[m][n] = sum_k x[m][k] * W[n][k] + b[n]
// M=1024, N=32768, K=512, fp32 in/out.
// Single-phase fused kernel, round 3: reg-stage fp32 -> convert -> XOR-swizzled
// double-buffered LDS, raw barrier (lgkm-only). Key change vs round 2:
// __builtin_amdgcn_sched_barrier(0) at every phase boundary. Rounds 1-2 showed
// VGPR_Count=108: the compiler hoisted the register-only fp32->bf16 converts
// above the barrier (rule: "memory" clobbers don't order non-memory instrs),
// dragging the prefetch's vmcnt(0) wait with them and killing the pipeline.
// sched_barrier(0) is the only fence nothing can cross.

typedef __bf16 bf16x8 __attribute__((ext_vector_type(8)));
typedef float  f32x4  __attribute__((ext_vector_type(4)));

#define MM 1024
#define NN 32768
#define KD 512
#define BM 128
#define BN 128
#define BK 64
#define NKT (KD / BK)   // 8

#define SCHED_FENCE() __builtin_amdgcn_sched_barrier(0)

// 16B-chunk swizzle within a 64-bf16 (128 B) row: uniform spread on both
// ds_write_b128 and ds_read_b128.
__device__ __forceinline__ int swz(int row, int ch) {
    return ch ^ (row & 7) ^ ((row >> 3) & 3);
}

__global__ __launch_bounds__(256, 2)
void gemm_fused_bias(const float* __restrict__ X, const float* __restrict__ W,
                     const float* __restrict__ Bv, float* __restrict__ Out)
{
    __shared__ __bf16 As[2][BM * BK];   // 2 x 16 KB
    __shared__ __bf16 Bs[2][BN * BK];   // 2 x 16 KB

    const int tid  = threadIdx.x;
    const int lane = tid & 63;
    const int ln15 = lane & 15;
    const int quad = lane >> 4;
    const int wave = tid >> 6;
    const int wr   = wave >> 1;
    const int wc   = wave & 1;

    // XCD swizzle: 8 consecutive same-XCD blocks share one W panel (L2 reuse).
    const int blk = (int)blockIdx.x;
    const int xcd = blk & 7;
    const int bm  = (blk >> 3) & 7;          // M/128 = 8
    const int bn  = xcd * 32 + (blk >> 6);   // N/128 = 256

    // staging: thread t owns row t>>1, fp32 cols (t&1)*32 .. +31 of each tile
    const int srow  = tid >> 1;
    const int shalf = tid & 1;
    const float* Ag = X + (size_t)(bm * BM + srow) * KD + shalf * 32;
    const float* Bg = W + (size_t)(bn * BN + srow) * KD + shalf * 32;

    f32x4 acc[4][4];
#pragma unroll
    for (int i = 0; i < 4; ++i)
#pragma unroll
        for (int j = 0; j < 4; ++j)
            acc[i][j] = (f32x4){0.f, 0.f, 0.f, 0.f};

    // prologue: issue K-step 0 loads (16 x dwordx4)
    f32x4 av[8], bv[8];
#pragma unroll
    for (int c = 0; c < 4; ++c) {
        av[2*c]   = *(const f32x4*)(Ag + c * 8);
        av[2*c+1] = *(const f32x4*)(Ag + c * 8 + 4);
        bv[2*c]   = *(const f32x4*)(Bg + c * 8);
        bv[2*c+1] = *(const f32x4*)(Bg + c * 8 + 4);
    }

    const int n0 = bn * BN + wc * 64 + ln15;
    float bias[4];
#pragma unroll
    for (int j = 0; j < 4; ++j) bias[j] = Bv[n0 + j * 16];

#pragma unroll 2
    for (int kt = 0; kt < NKT; ++kt) {
        // ---- phase 1: convert current regs -> bf16, swizzled LDS write ----
        SCHED_FENCE();   // converts may not hoist above prior MFMA phase
        __bf16* Aw = As[kt & 1] + srow * BK;
        __bf16* Bw = Bs[kt & 1] + srow * BK;
#pragma unroll
        for (int c = 0; c < 4; ++c) {
            const int ch = shalf * 4 + c;
            bf16x8 oa, ob;
#pragma unroll
            for (int e = 0; e < 4; ++e) {
                oa[e]     = (__bf16)av[2*c][e];
                oa[e + 4] = (__bf16)av[2*c + 1][e];
                ob[e]     = (__bf16)bv[2*c][e];
                ob[e + 4] = (__bf16)bv[2*c + 1][e];
            }
            *(bf16x8*)(Aw + swz(srow, ch) * 8) = oa;
            *(bf16x8*)(Bw + swz(srow, ch) * 8) = ob;
        }
        SCHED_FENCE();

        // ---- phase 2: issue next K-step's loads (stay in flight across
        //      the raw barrier, retire under the MFMA phase) ----
        if (kt + 1 < NKT) {
            const int ko = (kt + 1) * BK;
#pragma unroll
            for (int c = 0; c < 4; ++c) {
                av[2*c]   = *(const f32x4*)(Ag + ko + c * 8);
                av[2*c+1] = *(const f32x4*)(Ag + ko + c * 8 + 4);
                bv[2*c]   = *(const f32x4*)(Bg + ko + c * 8);
                bv[2*c+1] = *(const f32x4*)(Bg + ko + c * 8 + 4);
            }
        }
        SCHED_FENCE();

        // ---- phase 3: publish LDS writes (lgkm only, vmcnt NOT drained) ----
        asm volatile("s_waitcnt lgkmcnt(0)" ::: "memory");
        __builtin_amdgcn_s_barrier();
        SCHED_FENCE();

        // ---- phase 4: ds_read fragments + MFMA on buf[kt&1] ----
        const __bf16* Ar = As[kt & 1];
        const __bf16* Br = Bs[kt & 1];
#pragma unroll
        for (int kk = 0; kk < 2; ++kk) {
            bf16x8 af[4], bfr[4];
#pragma unroll
            for (int i = 0; i < 4; ++i) {
                const int ar = wr * 64 + i * 16 + ln15;
                af[i] = *(const bf16x8*)(Ar + ar * BK + swz(ar, kk * 4 + quad) * 8);
            }
#pragma unroll
            for (int j = 0; j < 4; ++j) {
                const int br = wc * 64 + j * 16 + ln15;
                bfr[j] = *(const bf16x8*)(Br + br * BK + swz(br, kk * 4 + quad) * 8);
            }
#pragma unroll
            for (int i = 0; i < 4; ++i)
#pragma unroll
                for (int j = 0; j < 4; ++j)
                    acc[i][j] = __builtin_amdgcn_mfma_f32_16x16x32_bf16(
                        af[i], bfr[j], acc[i][j], 0, 0, 0);
        }
        SCHED_FENCE();
    }

    // epilogue: C/D layout col=lane&15, row=quad*4+reg (verified prior session)
    const int m0 = bm * BM + wr * 64 + quad * 4;
#pragma unroll
    for (int i = 0; i < 4; ++i) {
#pragma unroll
        for (int r = 0; r < 4; ++r) {
            float* o = Out + (size_t)(m0 + i * 16 + r) * NN + n0;
#pragma unroll
            for (int j = 0; j < 4; ++j)
                o[j * 16] = acc[i][j][r] + bias[j];
        }
    }
}

extern "C" void kernel_launch(void* const* d_in, const int* in_sizes, int n_in,
                              void* d_out, int out_size, void* d_ws, size_t ws_size,
                              hipStream_t stream) {
    const float* x = (const float*)d_in[0];
    const float* W = (const float*)d_in[1];
    const float* b = (const float*)d_in[2];
    (void)d_ws; (void)ws_size; (void)in_sizes; (void)n_in; (void)out_size;
    const int grid = (MM / BM) * (NN / BN);   // 2048
    gemm_fused_bias<<<dim3(grid), dim3(256), 0, stream>>>(x, W, b, (float*)d_out);
}

// Round 4
// 240.692 us; speedup vs baseline: 1.1991x; 1.1991x over previous
//
#include <hip/hip_runtime.h>
#include <hip/hip_bf16.h>

// out[m][n] = sum_k x[m][k] * W[n][k] + b[n]
// M=1024, N=32768, K=512, fp32 in/out.
// Two-phase: (1) convert W,x to bf16 in d_ws; (2) MFMA GEMM with the
// T3-minimum schedule: double-buffered global_load_lds staging, DMAs for
// tile kt+1 issued BEFORE the MFMA phase on tile kt, one raw s_barrier +
// per-wave vmcnt(0) per K-step AFTER MFMA (no __syncthreads vmcnt-drain).

typedef __bf16 bf16x8 __attribute__((ext_vector_type(8)));
typedef __bf16 bf16x4 __attribute__((ext_vector_type(4)));
typedef float  f32x4  __attribute__((ext_vector_type(4)));

#define MM 1024
#define NN 32768
#define KD 512
#define BM 128
#define BN 128
#define BK 64
#define NKT (KD / BK)   // 8

#define WB_BYTES ((size_t)NN * KD * 2)              // 33,554,432
#define XB_BYTES ((size_t)MM * KD * 2)              //  1,048,576
#define WS_NEED  (WB_BYTES + XB_BYTES)

#define SCHED_FENCE() __builtin_amdgcn_sched_barrier(0)

// ---------------------------------------------------------------------------
// Phase 1: fp32 -> bf16 conversion of W (64 MB) and x (2 MB). Memory-bound.
// ---------------------------------------------------------------------------
__global__ __launch_bounds__(256)
void convert_to_bf16(const float* __restrict__ W, const float* __restrict__ X,
                     __bf16* __restrict__ Wb, __bf16* __restrict__ Xb)
{
    const int WCH = (NN * KD) / 8;   // 2,097,152 chunks of 8 floats
    const int XCH = (MM * KD) / 8;   //    65,536
    int stride = gridDim.x * blockDim.x;
    for (int c = blockIdx.x * blockDim.x + threadIdx.x; c < WCH + XCH; c += stride) {
        const float* src; __bf16* dst; int cc;
        if (c < WCH) { src = W; dst = Wb; cc = c; }
        else         { src = X; dst = Xb; cc = c - WCH; }
        f32x4 v0 = *(const f32x4*)(src + (size_t)cc * 8);
        f32x4 v1 = *(const f32x4*)(src + (size_t)cc * 8 + 4);
        bf16x8 o;
        o[0]=(__bf16)v0[0]; o[1]=(__bf16)v0[1]; o[2]=(__bf16)v0[2]; o[3]=(__bf16)v0[3];
        o[4]=(__bf16)v1[0]; o[5]=(__bf16)v1[1]; o[6]=(__bf16)v1[2]; o[7]=(__bf16)v1[3];
        *(bf16x8*)(dst + (size_t)cc * 8) = o;
    }
}

// ---------------------------------------------------------------------------
// Phase 2: bf16 GEMM, T3-minimum double-buffered schedule.
// LDS tile layout identical to the verified round-0 kernel: [row][BK]
// row-major, 16B chunks XOR-swizzled by (row&7) via the GLOBAL source address
// (gload_lds LDS dest is wave-base + lane*16, linear).
// ---------------------------------------------------------------------------
__global__ __launch_bounds__(256, 2)
void gemm_bf16_db(const __bf16* __restrict__ Xb, const __bf16* __restrict__ Wb,
                  const float* __restrict__ Bv, float* __restrict__ Out)
{
    __shared__ __bf16 As[2][BM * BK];   // 2 x 16 KB
    __shared__ __bf16 Bs[2][BN * BK];   // 2 x 16 KB   (64 KB total)

    const int tid  = threadIdx.x;
    const int lane = tid & 63;
    const int wave = tid >> 6;
    const int ln15 = lane & 15;
    const int quad = lane >> 4;
    const int wr   = wave >> 1;
    const int wc   = wave & 1;

    // XCD swizzle: 8 consecutive same-XCD blocks share one W panel (L2 reuse).
    const int blk = (int)blockIdx.x;
    const int xcd = blk & 7;
    const int bm  = (blk >> 3) & 7;          // M/128 = 8
    const int bn  = xcd * 32 + (blk >> 6);   // N/128 = 256

    // staging: wave w stages segments [w*4, w*4+4); 1 seg = 8 rows x 64 bf16.
    const int srow   = lane >> 3;   // row within segment, 0..7
    const int chunkL = lane & 7;    // LDS 16B-chunk slot within row
    const int gch    = chunkL ^ srow;   // XOR swizzle applied on global source

    const __bf16* Ag = Xb + (size_t)(bm * BM) * KD;
    const __bf16* Bg = Wb + (size_t)(bn * BN) * KD;

    f32x4 acc[4][4];
#pragma unroll
    for (int i = 0; i < 4; ++i)
#pragma unroll
        for (int j = 0; j < 4; ++j)
            acc[i][j] = (f32x4){0.f, 0.f, 0.f, 0.f};

#define STAGE(buf, kt_) do {                                                       \
    const int k0_ = (kt_) * BK;                                                    \
    _Pragma("unroll")                                                              \
    for (int i_ = 0; i_ < 4; ++i_) {                                               \
        const int seg_ = wave * 4 + i_;                                            \
        const int row_ = seg_ * 8 + srow;                                          \
        __builtin_amdgcn_global_load_lds(                                          \
            (const __attribute__((address_space(1))) void*)(Ag + (size_t)row_ * KD + k0_ + gch * 8), \
            (__attribute__((address_space(3))) void*)(&As[buf][seg_ * 512 + lane * 8]), 16, 0, 0);   \
        __builtin_amdgcn_global_load_lds(                                          \
            (const __attribute__((address_space(1))) void*)(Bg + (size_t)row_ * KD + k0_ + gch * 8), \
            (__attribute__((address_space(3))) void*)(&Bs[buf][seg_ * 512 + lane * 8]), 16, 0, 0);   \
    }                                                                              \
} while (0)

    // prologue: stage tile 0 into buf 0, publish it
    STAGE(0, 0);
    asm volatile("s_waitcnt vmcnt(0)" ::: "memory");
    __builtin_amdgcn_s_barrier();
    SCHED_FENCE();

#pragma unroll 1
    for (int kt = 0; kt < NKT; ++kt) {
        const int cur = kt & 1;

        // issue next tile's DMAs first: they fly under the MFMA phase below
        if (kt + 1 < NKT) STAGE(cur ^ 1, kt + 1);
        SCHED_FENCE();

        // fragment reads + MFMA on buf[cur]
#pragma unroll
        for (int kk = 0; kk < 2; ++kk) {
            bf16x8 af[4], bfr[4];
#pragma unroll
            for (int i = 0; i < 4; ++i) {
                const int ar = wr * 64 + i * 16 + ln15;
                af[i] = *(const bf16x8*)(&As[cur][ar * 64 + (((kk * 4 + quad) ^ (ar & 7)) * 8)]);
            }
#pragma unroll
            for (int j = 0; j < 4; ++j) {
                const int br = wc * 64 + j * 16 + ln15;
                bfr[j] = *(const bf16x8*)(&Bs[cur][br * 64 + (((kk * 4 + quad) ^ (br & 7)) * 8)]);
            }
#pragma unroll
            for (int i = 0; i < 4; ++i)
#pragma unroll
                for (int j = 0; j < 4; ++j)
                    acc[i][j] = __builtin_amdgcn_mfma_f32_16x16x32_bf16(
                        af[i], bfr[j], acc[i][j], 0, 0, 0);
        }
        SCHED_FENCE();

        // publish next tile: my DMAs done (vmcnt only -- they had the whole
        // MFMA phase to complete), then raw barrier. No lgkm drain needed:
        // frag-read results were consumed by MFMA (compiler-inserted waits).
        if (kt + 1 < NKT) {
            asm volatile("s_waitcnt vmcnt(0)" ::: "memory");
            __builtin_amdgcn_s_barrier();
            SCHED_FENCE();
        }
    }
#undef STAGE

    // epilogue: C/D layout col=lane&15, row=quad*4+reg (verified prior session)
    const int n0 = bn * BN + wc * 64 + ln15;
    const int m0 = bm * BM + wr * 64 + quad * 4;
    float bias[4];
#pragma unroll
    for (int j = 0; j < 4; ++j) bias[j] = Bv[n0 + j * 16];

#pragma unroll
    for (int i = 0; i < 4; ++i) {
#pragma unroll
        for (int r = 0; r < 4; ++r) {
            float* o = Out + (size_t)(m0 + i * 16 + r) * NN + n0;
#pragma unroll
            for (int j = 0; j < 4; ++j)
                o[j * 16] = acc[i][j][r] + bias[j];
        }
    }
}

// ---------------------------------------------------------------------------
// Fallback: fp32 staging with in-kernel convert (verified in prior session).
// Used only if ws_size is too small for the bf16 scratch copies.
// ---------------------------------------------------------------------------
#define LDT 72
__global__ __launch_bounds__(256, 2)
void gemm_bias_fallback(const float* __restrict__ X, const float* __restrict__ W,
                        const float* __restrict__ Bv, float* __restrict__ Out)
{
    __shared__ __bf16 As[BM * LDT];
    __shared__ __bf16 Bs[BN * LDT];

    const int tid  = threadIdx.x;
    const int lane = tid & 63;
    const int wave = tid >> 6;
    const int wr   = wave >> 1;
    const int wc   = wave & 1;
    const int ln15 = lane & 15;
    const int quad = lane >> 4;

    const int blk = blockIdx.x;
    const int xcd = blk & 7;
    const int bm  = (blk >> 3) & 7;
    const int bn  = xcd * 32 + (blk >> 6);

    const int r0 = tid >> 4;
    const int c4 = (tid & 15) << 2;
    const float* aG = X + (size_t)(bm * BM + r0) * KD + c4;
    const float* bG = W + (size_t)(bn * BN + r0) * KD + c4;
    __bf16* aS = &As[r0 * LDT + c4];
    __bf16* bS = &Bs[r0 * LDT + c4];

    const int aBase = (wr * 64 + ln15) * LDT + quad * 8;
    const int bBase = (wc * 64 + ln15) * LDT + quad * 8;

    f32x4 acc[4][4];
#pragma unroll
    for (int i = 0; i < 4; ++i)
#pragma unroll
        for (int j = 0; j < 4; ++j)
            acc[i][j] = (f32x4){0.f, 0.f, 0.f, 0.f};

#pragma unroll 1
    for (int kt = 0; kt < KD / BK; ++kt) {
        float4 av[8], bv[8];
#pragma unroll
        for (int i = 0; i < 8; ++i) {
            av[i] = *(const float4*)(aG + (size_t)i * 16 * KD);
            bv[i] = *(const float4*)(bG + (size_t)i * 16 * KD);
        }
        aG += BK; bG += BK;

        __syncthreads();
#pragma unroll
        for (int i = 0; i < 8; ++i) {
            bf16x4 a4, b4;
            a4[0] = (__bf16)av[i].x; a4[1] = (__bf16)av[i].y;
            a4[2] = (__bf16)av[i].z; a4[3] = (__bf16)av[i].w;
            b4[0] = (__bf16)bv[i].x; b4[1] = (__bf16)bv[i].y;
            b4[2] = (__bf16)bv[i].z; b4[3] = (__bf16)bv[i].w;
            *(bf16x4*)(aS + i * 16 * LDT) = a4;
            *(bf16x4*)(bS + i * 16 * LDT) = b4;
        }
        __syncthreads();

#pragma unroll
        for (int kk = 0; kk < 2; ++kk) {
            bf16x8 af[4], bfr[4];
#pragma unroll
            for (int i = 0; i < 4; ++i)
                af[i] = *(const bf16x8*)(&As[aBase + kk * 32 + i * 16 * LDT]);
#pragma unroll
            for (int j = 0; j < 4; ++j)
                bfr[j] = *(const bf16x8*)(&Bs[bBase + kk * 32 + j * 16 * LDT]);
#pragma unroll
            for (int i = 0; i < 4; ++i)
#pragma unroll
                for (int j = 0; j < 4; ++j)
                    acc[i][j] = __builtin_amdgcn_mfma_f32_16x16x32_bf16(
                        af[i], bfr[j], acc[i][j], 0, 0, 0);
        }
    }

    const int n0 = bn * BN + wc * 64 + ln15;
    const int m0 = bm * BM + wr * 64 + quad * 4;
    float bias[4];
#pragma unroll
    for (int j = 0; j < 4; ++j) bias[j] = Bv[n0 + j * 16];

#pragma unroll
    for (int i = 0; i < 4; ++i) {
#pragma unroll
        for (int r = 0; r < 4; ++r) {
            float* o = Out + (size_t)(m0 + i * 16 + r) * NN + n0;
#pragma unroll
            for (int j = 0; j < 4; ++j)
                o[j * 16] = acc[i][j][r] + bias[j];
        }
    }
}

extern "C" void kernel_launch(void* const* d_in, const int* in_sizes, int n_in,
                              void* d_out, int out_size, void* d_ws, size_t ws_size,
                              hipStream_t stream) {
    const float* x = (const float*)d_in[0];
    const float* W = (const float*)d_in[1];
    const float* b = (const float*)d_in[2];
    float* out = (float*)d_out;
    const int grid = (MM / BM) * (NN / BN);   // 2048

    if (ws_size >= WS_NEED) {
        __bf16* Wb = (__bf16*)d_ws;
        __bf16* Xb = (__bf16*)((char*)d_ws + WB_BYTES);
        convert_to_bf16<<<dim3(4096), dim3(256), 0, stream>>>(W, x, Wb, Xb);
        gemm_bf16_db<<<dim3(grid), dim3(256), 0, stream>>>(Xb, Wb, b, out);
    } else {
        gemm_bias_fallback<<<dim3(grid), dim3(256), 0, stream>>>(x, W, b, out);
    }
}

// Round 5
// 237.683 us; speedup vs baseline: 1.2142x; 1.0127x over previous
//
#include <hip/hip_runtime.h>
#include <hip/hip_bf16.h>

// out[m][n] = sum_k x[m][k] * W[n][k] + b[n]
// M=1024, N=32768, K=512, fp32 in/out.
// Two-phase: (1) convert W,x to bf16 in d_ws; (2) MFMA GEMM with a DEPTH-2
// prefetch pipeline: BK=32 tiles, 3-slot LDS ring (48 KB -> 3 blocks/CU),
// tile kt+2 staged during tile kt (DMA flight = one full tile phase),
// counted s_waitcnt vmcnt(4) at tile boundaries (never 0 until the tail).

typedef __bf16 bf16x8 __attribute__((ext_vector_type(8)));
typedef __bf16 bf16x4 __attribute__((ext_vector_type(4)));
typedef float  f32x4  __attribute__((ext_vector_type(4)));

#define MM 1024
#define NN 32768
#define KD 512
#define BM 128
#define BN 128
#define BK 32
#define NKT (KD / BK)   // 16

#define WB_BYTES ((size_t)NN * KD * 2)              // 33,554,432
#define XB_BYTES ((size_t)MM * KD * 2)              //  1,048,576
#define WS_NEED  (WB_BYTES + XB_BYTES)

#define SCHED_FENCE() __builtin_amdgcn_sched_barrier(0)

// ---------------------------------------------------------------------------
// Phase 1: fp32 -> bf16 conversion of W (64 MB) and x (2 MB). Memory-bound.
// ---------------------------------------------------------------------------
__global__ __launch_bounds__(256)
void convert_to_bf16(const float* __restrict__ W, const float* __restrict__ X,
                     __bf16* __restrict__ Wb, __bf16* __restrict__ Xb)
{
    const int WCH = (NN * KD) / 8;   // 2,097,152 chunks of 8 floats
    const int XCH = (MM * KD) / 8;   //    65,536
    int stride = gridDim.x * blockDim.x;
    for (int c = blockIdx.x * blockDim.x + threadIdx.x; c < WCH + XCH; c += stride) {
        const float* src; __bf16* dst; int cc;
        if (c < WCH) { src = W; dst = Wb; cc = c; }
        else         { src = X; dst = Xb; cc = c - WCH; }
        f32x4 v0 = *(const f32x4*)(src + (size_t)cc * 8);
        f32x4 v1 = *(const f32x4*)(src + (size_t)cc * 8 + 4);
        bf16x8 o;
        o[0]=(__bf16)v0[0]; o[1]=(__bf16)v0[1]; o[2]=(__bf16)v0[2]; o[3]=(__bf16)v0[3];
        o[4]=(__bf16)v1[0]; o[5]=(__bf16)v1[1]; o[6]=(__bf16)v1[2]; o[7]=(__bf16)v1[3];
        *(bf16x8*)(dst + (size_t)cc * 8) = o;
    }
}

// ---------------------------------------------------------------------------
// Phase 2: bf16 GEMM, depth-2 / 3-ring schedule.
// LDS tile: [row][BK=32] row-major, 4 chunks of 16B per row, chunk swizzle
// f(r) = (r&3)^((r>>2)&3) applied on the GLOBAL source address (gload_lds LDS
// dest is wave-base + lane*16, linear) and inverted on the ds_read side.
// ---------------------------------------------------------------------------
__global__ __launch_bounds__(256, 3)
void gemm_bf16_d2(const __bf16* __restrict__ Xb, const __bf16* __restrict__ Wb,
                  const float* __restrict__ Bv, float* __restrict__ Out)
{
    __shared__ __bf16 As[3][BM * BK];   // 3 x 8 KB
    __shared__ __bf16 Bs[3][BN * BK];   // 3 x 8 KB   (48 KB total)

    const int tid  = threadIdx.x;
    const int lane = tid & 63;
    const int wave = tid >> 6;
    const int ln15 = lane & 15;
    const int quad = lane >> 4;
    const int wr   = wave >> 1;
    const int wc   = wave & 1;

    // XCD swizzle: 8 consecutive same-XCD blocks share one W panel (L2 reuse).
    const int blk = (int)blockIdx.x;
    const int xcd = blk & 7;
    const int bm  = (blk >> 3) & 7;          // M/128 = 8
    const int bn  = xcd * 32 + (blk >> 6);   // N/128 = 256

    const __bf16* Ag = Xb + (size_t)(bm * BM) * KD;
    const __bf16* Bg = Wb + (size_t)(bn * BN) * KD;

    f32x4 acc[4][4];
#pragma unroll
    for (int i = 0; i < 4; ++i)
#pragma unroll
        for (int j = 0; j < 4; ++j)
            acc[i][j] = (f32x4){0.f, 0.f, 0.f, 0.f};

    // read-side swizzled chunk: independent of frag index i (rows step by 16)
    const int physch = quad ^ (ln15 & 3) ^ ((ln15 >> 2) & 3);

    // staging: thread covers 16B chunks ci = wave*128 + l*64 + lane, l=0,1
    // (512 chunks = 128 rows x 4 chunks). row = ci>>2, phys chunk = ci&3,
    // source logical chunk g = (ci&3) ^ f(row).
#define STAGE(buf_, kt_) do {                                                       \
    const int k0_ = (kt_) * BK;                                                     \
    _Pragma("unroll")                                                               \
    for (int l_ = 0; l_ < 2; ++l_) {                                                \
        const int ci_  = wave * 128 + l_ * 64 + lane;                               \
        const int row_ = ci_ >> 2;                                                  \
        const int g_   = (ci_ & 3) ^ (row_ & 3) ^ ((row_ >> 2) & 3);                \
        __builtin_amdgcn_global_load_lds(                                           \
            (const __attribute__((address_space(1))) void*)(Ag + (size_t)row_ * KD + k0_ + g_ * 8), \
            (__attribute__((address_space(3))) void*)(&As[buf_][ci_ * 8]), 16, 0, 0);               \
        __builtin_amdgcn_global_load_lds(                                           \
            (const __attribute__((address_space(1))) void*)(Bg + (size_t)row_ * KD + k0_ + g_ * 8), \
            (__attribute__((address_space(3))) void*)(&Bs[buf_][ci_ * 8]), 16, 0, 0);               \
    }                                                                               \
} while (0)

    // prologue: stage tiles 0 and 1; wait only tile 0 (vmcnt(4) leaves tile 1
    // in flight), publish.
    STAGE(0, 0);
    STAGE(1, 1);
    asm volatile("s_waitcnt vmcnt(4)" ::: "memory");
    __builtin_amdgcn_s_barrier();
    SCHED_FENCE();

#pragma unroll 1
    for (int kt = 0; kt < NKT; ++kt) {
        const int cur = kt % 3;

        // depth-2: issue tile kt+2's DMAs into buf[(kt+2)%3] (= buf[(kt-1)%3],
        // whose reads all retired before the barrier that ended tile kt-1).
        if (kt + 2 < NKT) STAGE((kt + 2) % 3, kt + 2);
        SCHED_FENCE();

        // fragment reads + MFMA on buf[cur]
        bf16x8 af[4], bfr[4];
#pragma unroll
        for (int i = 0; i < 4; ++i) {
            const int ar = wr * 64 + i * 16 + ln15;
            af[i] = *(const bf16x8*)(&As[cur][ar * BK + physch * 8]);
        }
#pragma unroll
        for (int j = 0; j < 4; ++j) {
            const int br = wc * 64 + j * 16 + ln15;
            bfr[j] = *(const bf16x8*)(&Bs[cur][br * BK + physch * 8]);
        }
        __builtin_amdgcn_s_setprio(1);
#pragma unroll
        for (int i = 0; i < 4; ++i)
#pragma unroll
            for (int j = 0; j < 4; ++j)
                acc[i][j] = __builtin_amdgcn_mfma_f32_16x16x32_bf16(
                    af[i], bfr[j], acc[i][j], 0, 0, 0);
        __builtin_amdgcn_s_setprio(0);
        SCHED_FENCE();

        // tile boundary: counted wait (tile kt+1's 4 loads drained, kt+2's 4
        // stay in flight), raw barrier. Tail: kt=14 needs tile 15 fully landed.
        if (kt + 1 < NKT) {
            if (kt + 2 < NKT) asm volatile("s_waitcnt vmcnt(4)" ::: "memory");
            else              asm volatile("s_waitcnt vmcnt(0)" ::: "memory");
            __builtin_amdgcn_s_barrier();
            SCHED_FENCE();
        }
    }
#undef STAGE

    // epilogue: bias loads kept OUT of the K-loop so they never enter the
    // vmcnt counting. C/D layout col=lane&15, row=quad*4+reg (verified).
    const int n0 = bn * BN + wc * 64 + ln15;
    const int m0 = bm * BM + wr * 64 + quad * 4;
    float bias[4];
#pragma unroll
    for (int j = 0; j < 4; ++j) bias[j] = Bv[n0 + j * 16];

#pragma unroll
    for (int i = 0; i < 4; ++i) {
#pragma unroll
        for (int r = 0; r < 4; ++r) {
            float* o = Out + (size_t)(m0 + i * 16 + r) * NN + n0;
#pragma unroll
            for (int j = 0; j < 4; ++j)
                __builtin_nontemporal_store(acc[i][j][r] + bias[j], o + j * 16);
        }
    }
}

// ---------------------------------------------------------------------------
// Fallback: fp32 staging with in-kernel convert (verified in prior session).
// Used only if ws_size is too small for the bf16 scratch copies.
// ---------------------------------------------------------------------------
#define LDT 72
#define FBK 64
__global__ __launch_bounds__(256, 2)
void gemm_bias_fallback(const float* __restrict__ X, const float* __restrict__ W,
                        const float* __restrict__ Bv, float* __restrict__ Out)
{
    __shared__ __bf16 As[BM * LDT];
    __shared__ __bf16 Bs[BN * LDT];

    const int tid  = threadIdx.x;
    const int lane = tid & 63;
    const int wave = tid >> 6;
    const int wr   = wave >> 1;
    const int wc   = wave & 1;
    const int ln15 = lane & 15;
    const int quad = lane >> 4;

    const int blk = blockIdx.x;
    const int xcd = blk & 7;
    const int bm  = (blk >> 3) & 7;
    const int bn  = xcd * 32 + (blk >> 6);

    const int r0 = tid >> 4;
    const int c4 = (tid & 15) << 2;
    const float* aG = X + (size_t)(bm * BM + r0) * KD + c4;
    const float* bG = W + (size_t)(bn * BN + r0) * KD + c4;
    __bf16* aS = &As[r0 * LDT + c4];
    __bf16* bS = &Bs[r0 * LDT + c4];

    const int aBase = (wr * 64 + ln15) * LDT + quad * 8;
    const int bBase = (wc * 64 + ln15) * LDT + quad * 8;

    f32x4 acc[4][4];
#pragma unroll
    for (int i = 0; i < 4; ++i)
#pragma unroll
        for (int j = 0; j < 4; ++j)
            acc[i][j] = (f32x4){0.f, 0.f, 0.f, 0.f};

#pragma unroll 1
    for (int kt = 0; kt < KD / FBK; ++kt) {
        float4 av[8], bv[8];
#pragma unroll
        for (int i = 0; i < 8; ++i) {
            av[i] = *(const float4*)(aG + (size_t)i * 16 * KD);
            bv[i] = *(const float4*)(bG + (size_t)i * 16 * KD);
        }
        aG += FBK; bG += FBK;

        __syncthreads();
#pragma unroll
        for (int i = 0; i < 8; ++i) {
            bf16x4 a4, b4;
            a4[0] = (__bf16)av[i].x; a4[1] = (__bf16)av[i].y;
            a4[2] = (__bf16)av[i].z; a4[3] = (__bf16)av[i].w;
            b4[0] = (__bf16)bv[i].x; b4[1] = (__bf16)bv[i].y;
            b4[2] = (__bf16)bv[i].z; b4[3] = (__bf16)bv[i].w;
            *(bf16x4*)(aS + i * 16 * LDT) = a4;
            *(bf16x4*)(bS + i * 16 * LDT) = b4;
        }
        __syncthreads();

#pragma unroll
        for (int kk = 0; kk < 2; ++kk) {
            bf16x8 af[4], bfr[4];
#pragma unroll
            for (int i = 0; i < 4; ++i)
                af[i] = *(const bf16x8*)(&As[aBase + kk * 32 + i * 16 * LDT]);
#pragma unroll
            for (int j = 0; j < 4; ++j)
                bfr[j] = *(const bf16x8*)(&Bs[bBase + kk * 32 + j * 16 * LDT]);
#pragma unroll
            for (int i = 0; i < 4; ++i)
#pragma unroll
                for (int j = 0; j < 4; ++j)
                    acc[i][j] = __builtin_amdgcn_mfma_f32_16x16x32_bf16(
                        af[i], bfr[j], acc[i][j], 0, 0, 0);
        }
    }

    const int n0 = bn * BN + wc * 64 + ln15;
    const int m0 = bm * BM + wr * 64 + quad * 4;
    float bias[4];
#pragma unroll
    for (int j = 0; j < 4; ++j) bias[j] = Bv[n0 + j * 16];

#pragma unroll
    for (int i = 0; i < 4; ++i) {
#pragma unroll
        for (int r = 0; r < 4; ++r) {
            float* o = Out + (size_t)(m0 + i * 16 + r) * NN + n0;
#pragma unroll
            for (int j = 0; j < 4; ++j)
                o[j * 16] = acc[i][j][r] + bias[j];
        }
    }
}

extern "C" void kernel_launch(void* const* d_in, const int* in_sizes, int n_in,
                              void* d_out, int out_size, void* d_ws, size_t ws_size,
                              hipStream_t stream) {
    const float* x = (const float*)d_in[0];
    const float* W = (const float*)d_in[1];
    const float* b = (const float*)d_in[2];
    float* out = (float*)d_out;
    const int grid = (MM / BM) * (NN / BN);   // 2048

    if (ws_size >= WS_NEED) {
        __bf16* Wb = (__bf16*)d_ws;
        __bf16* Xb = (__bf16*)((char*)d_ws + WB_BYTES);
        convert_to_bf16<<<dim3(4096), dim3(256), 0, stream>>>(W, x, Wb, Xb);
        gemm_bf16_d2<<<dim3(grid), dim3(256), 0, stream>>>(Xb, Wb, b, out);
    } else {
        gemm_bias_fallback<<<dim3(grid), dim3(256), 0, stream>>>(x, W, b, out);
    }
}